// Round 3
// baseline (2280.416 us; speedup 1.0000x reference)
//
#include <hip/hip_runtime.h>

#define FD 128    // hidden feature dim
#define OD 64     // output dim
#define KC 32     // privatized histogram copies for deg_out
#define RB 64     // nodes per bucket (dst >> 6)
#define CHUNKS 256
#define NBMAX 1024

// ---------------- deg_out (privatized histogram) ----------------

__global__ void zero_kernel(int* __restrict__ a, int n) {
    int i = blockIdx.x * 256 + threadIdx.x;
    if (i < n) a[i] = 0;
}

__global__ void count_src_kernel(const int* __restrict__ src, int* __restrict__ cnt,
                                 int E, int N) {
    int e = blockIdx.x * 256 + threadIdx.x;
    int k = blockIdx.x & (KC - 1);
    if (e < E) atomicAdd(&cnt[k * N + src[e]], 1);
}

__global__ void rout_kernel(const int* __restrict__ cnt, float* __restrict__ r_out, int N) {
    int v = blockIdx.x * 256 + threadIdx.x;
    if (v >= N) return;
    int s = 0;
    #pragma unroll
    for (int k = 0; k < KC; k++) s += cnt[k * N + v];
    r_out[v] = rsqrtf((float)max(s, 1));
}

// ---------------- coarse bucket partition (counting sort, contention-free) ----------------

// per-chunk per-bucket histogram
__global__ __launch_bounds__(256) void bucket_hist_kernel(const int* __restrict__ dst,
                                                          int* __restrict__ hist_g,
                                                          int E, int NB, int CS) {
    __shared__ int hist[NBMAX];
    int c = blockIdx.x;
    for (int t = threadIdx.x; t < NB; t += 256) hist[t] = 0;
    __syncthreads();
    int e1 = min(c * CS + CS, E);
    for (int e = c * CS + threadIdx.x; e < e1; e += 256)
        atomicAdd(&hist[dst[e] >> 6], 1);
    __syncthreads();
    for (int t = threadIdx.x; t < NB; t += 256) hist_g[c * NB + t] = hist[t];
}

// exclusive scan of bucket totals (NB <= 1024, single block)
__global__ __launch_bounds__(1024) void bucket_scan_kernel(const int* __restrict__ hist_g,
                                                           int* __restrict__ bstart,
                                                           int NB, int E) {
    __shared__ int wsum[16];
    int tid = threadIdx.x, lane = tid & 63, w = tid >> 6;
    int total = 0;
    if (tid < NB)
        for (int c = 0; c < CHUNKS; c++) total += hist_g[c * NB + tid];
    int x = total;
    #pragma unroll
    for (int d = 1; d < 64; d <<= 1) {
        int t = __shfl_up(x, d, 64);
        if (lane >= d) x += t;
    }
    if (lane == 63) wsum[w] = x;
    __syncthreads();
    if (w == 0) {
        int s = (lane < 16) ? wsum[lane] : 0;
        #pragma unroll
        for (int d = 1; d < 16; d <<= 1) {
            int t = __shfl_up(s, d, 64);
            if (lane >= d) s += t;
        }
        if (lane < 16) wsum[lane] = s;
    }
    __syncthreads();
    int off = (w == 0) ? 0 : wsum[w - 1];
    if (tid < NB) bstart[tid] = x + off - total;
    if (tid == 0) bstart[NB] = E;
}

// cursor[c][b] = bstart[b] + prefix over chunks (coalesced across threads)
__global__ void bucket_cursor_kernel(const int* __restrict__ hist_g, const int* __restrict__ bstart,
                                     int* __restrict__ cursor, int NB) {
    int b = blockIdx.x * 256 + threadIdx.x;
    if (b >= NB) return;
    int run = bstart[b];
    for (int c = 0; c < CHUNKS; c++) {
        cursor[c * NB + b] = run;
        run += hist_g[c * NB + b];
    }
}

// scatter packed edges (dl<<17 | src) into bucket runs via LDS cursors
__global__ __launch_bounds__(256) void partition_kernel(const int* __restrict__ src,
                                                        const int* __restrict__ dst,
                                                        const int* __restrict__ cursor,
                                                        int* __restrict__ epack,
                                                        int E, int NB, int CS) {
    __shared__ int cur[NBMAX];
    int c = blockIdx.x;
    for (int t = threadIdx.x; t < NB; t += 256) cur[t] = cursor[c * NB + t];
    __syncthreads();
    int e1 = min(c * CS + CS, E);
    for (int e = c * CS + threadIdx.x; e < e1; e += 256) {
        int d = dst[e];
        int pos = atomicAdd(&cur[d >> 6], 1);
        epack[pos] = ((d & 63) << 17) | src[e];   // src < 2^17
    }
}

// ---------------- fused bucketed aggregation ----------------
// Z[v][f] = rin[v] * sum_{e: dst=v} (SCALE ? r_src[src_e] : 1) * X[src_e][f]  (+ bias[f])
template <int F, bool SCALE, bool CRIN, bool BIAS>
__global__ __launch_bounds__(512) void agg_fused_kernel(const float* __restrict__ X,
                                                        const float* __restrict__ r_src,
                                                        float* __restrict__ r_in_g,
                                                        const int* __restrict__ bstart,
                                                        const int* __restrict__ epack,
                                                        const float* __restrict__ bias,
                                                        float* __restrict__ Z, int N) {
    __shared__ float acc[RB * F];
    __shared__ float rin_s[RB];
    __shared__ int degs[RB];
    const int tid = threadIdx.x, lane = tid & 63, wv = tid >> 6;  // 8 waves
    const int b = blockIdx.x;
    const int base = b * RB;
    for (int i = tid; i < RB * F; i += 512) acc[i] = 0.f;
    if (CRIN && tid < RB) degs[tid] = 0;
    __syncthreads();

    const int s0 = bstart[b];
    const int cnt = bstart[b + 1] - s0;
    int i = wv;
    for (; i + 8 < cnt; i += 16) {
        int pk0 = epack[s0 + i];
        int pk1 = epack[s0 + i + 8];
        int sr0 = pk0 & 0x1FFFF, dl0 = pk0 >> 17;
        int sr1 = pk1 & 0x1FFFF, dl1 = pk1 >> 17;
        float w0 = SCALE ? r_src[sr0] : 1.f;
        float w1 = SCALE ? r_src[sr1] : 1.f;
        float x00 = X[(size_t)sr0 * F + lane];
        float x10 = X[(size_t)sr1 * F + lane];
        if (F == 128) {
            float x01 = X[(size_t)sr0 * F + 64 + lane];
            float x11 = X[(size_t)sr1 * F + 64 + lane];
            atomicAdd(&acc[dl0 * F + lane], x00 * w0);
            atomicAdd(&acc[dl0 * F + 64 + lane], x01 * w0);
            atomicAdd(&acc[dl1 * F + lane], x10 * w1);
            atomicAdd(&acc[dl1 * F + 64 + lane], x11 * w1);
        } else {
            atomicAdd(&acc[dl0 * F + lane], x00 * w0);
            atomicAdd(&acc[dl1 * F + lane], x10 * w1);
        }
        if (CRIN && lane == 0) { atomicAdd(&degs[dl0], 1); atomicAdd(&degs[dl1], 1); }
    }
    for (; i < cnt; i += 8) {
        int pk0 = epack[s0 + i];
        int sr0 = pk0 & 0x1FFFF, dl0 = pk0 >> 17;
        float w0 = SCALE ? r_src[sr0] : 1.f;
        float x00 = X[(size_t)sr0 * F + lane];
        atomicAdd(&acc[dl0 * F + lane], x00 * w0);
        if (F == 128) {
            float x01 = X[(size_t)sr0 * F + 64 + lane];
            atomicAdd(&acc[dl0 * F + 64 + lane], x01 * w0);
        }
        if (CRIN && lane == 0) atomicAdd(&degs[dl0], 1);
    }
    __syncthreads();

    if (tid < RB) {
        float ri;
        if (CRIN) {
            ri = rsqrtf((float)max(degs[tid], 1));
            if (base + tid < N) r_in_g[base + tid] = ri;
        } else {
            ri = (base + tid < N) ? r_in_g[base + tid] : 0.f;
        }
        rin_s[tid] = ri;
    }
    __syncthreads();
    for (int idx = tid; idx < RB * F; idx += 512) {
        int node = idx / F, f = idx - node * F;
        int gn = base + node;
        if (gn < N) {
            float vv = acc[idx] * rin_s[node];
            if (BIAS) vv += bias[f];
            Z[(size_t)gn * F + f] = vv;
        }
    }
}

// ---------------- GEMM: C(MxBN) = A(Mx128) * B(128xBN) + epilogue ----------------
// EPI 0: C = relu(acc + bias[col]) * rowscale[row] ;  EPI 2: C = acc
template <int BN, int TN, int EPI>
__global__ __launch_bounds__(256) void gemm_kernel(const float* __restrict__ A,
                                                   const float* __restrict__ B,
                                                   const float* __restrict__ bias,
                                                   const float* __restrict__ rowscale,
                                                   float* __restrict__ C, int M) {
    __shared__ float As[8][128];
    __shared__ float Bs[8][BN];
    const int tid = threadIdx.x;
    const int blk0 = blockIdx.x * 128;
    const int tr = tid >> 4;
    const int tc = tid & 15;

    float acc[8][TN];
    #pragma unroll
    for (int i = 0; i < 8; i++)
        #pragma unroll
        for (int j = 0; j < TN; j++) acc[i][j] = 0.f;

    const int lm = tid >> 1;
    const int lka = (tid & 1) * 4;
    const int arow = blk0 + lm;
    constexpr int bthr = (8 * BN) / 256;
    const int lkb = tid / (BN / bthr);
    const int lnb = (tid % (BN / bthr)) * bthr;

    for (int k0 = 0; k0 < 128; k0 += 8) {
        float4 av = make_float4(0.f, 0.f, 0.f, 0.f);
        if (arow < M) av = *(const float4*)(A + (size_t)arow * 128 + k0 + lka);
        float bv[bthr];
        #pragma unroll
        for (int j = 0; j < bthr; j++) bv[j] = B[(k0 + lkb) * BN + lnb + j];
        __syncthreads();
        As[lka + 0][lm] = av.x;
        As[lka + 1][lm] = av.y;
        As[lka + 2][lm] = av.z;
        As[lka + 3][lm] = av.w;
        #pragma unroll
        for (int j = 0; j < bthr; j++) Bs[lkb][lnb + j] = bv[j];
        __syncthreads();
        #pragma unroll
        for (int kk = 0; kk < 8; kk++) {
            float a[8], bb[TN];
            #pragma unroll
            for (int i = 0; i < 8; i++) a[i] = As[kk][tr * 8 + i];
            #pragma unroll
            for (int j = 0; j < TN; j++) bb[j] = Bs[kk][tc * TN + j];
            #pragma unroll
            for (int i = 0; i < 8; i++)
                #pragma unroll
                for (int j = 0; j < TN; j++) acc[i][j] += a[i] * bb[j];
        }
    }

    #pragma unroll
    for (int i = 0; i < 8; i++) {
        int row = blk0 + tr * 8 + i;
        if (row < M) {
            float rsc = (EPI == 0) ? rowscale[row] : 1.f;
            #pragma unroll
            for (int j = 0; j < TN; j++) {
                float vv = acc[i][j];
                if (EPI == 0) vv = fmaxf(vv + bias[tc * TN + j], 0.f) * rsc;
                C[(size_t)row * BN + tc * TN + j] = vv;
            }
        }
    }
}

// ---------------- fold W2@Wf, b2@Wf+bf ----------------
__global__ void fold_kernel(const float* __restrict__ W2, const float* __restrict__ Wf,
                            const float* __restrict__ b2, const float* __restrict__ bf,
                            float* __restrict__ Wc, float* __restrict__ bc) {
    int idx = blockIdx.x * 256 + threadIdx.x;
    if (idx < FD * OD) {
        int i = idx / OD, j = idx % OD;
        float s = 0.f;
        for (int k = 0; k < FD; k++) s += W2[i * FD + k] * Wf[k * OD + j];
        Wc[idx] = s;
    }
    if (idx < OD) {
        float s = bf[idx];
        for (int k = 0; k < FD; k++) s += b2[k] * Wf[k * OD + idx];
        bc[idx] = s;
    }
}

// ---------------- launch ----------------
extern "C" void kernel_launch(void* const* d_in, const int* in_sizes, int n_in,
                              void* d_out, int out_size, void* d_ws, size_t ws_size,
                              hipStream_t stream) {
    const float* in_feat = (const float*)d_in[0];
    const int*   src     = (const int*)d_in[1];
    const int*   dst     = (const int*)d_in[2];
    const float* W1      = (const float*)d_in[3];
    const float* b1      = (const float*)d_in[4];
    const float* W2      = (const float*)d_in[5];
    const float* b2      = (const float*)d_in[6];
    const float* Wf      = (const float*)d_in[7];
    const float* bf      = (const float*)d_in[8];
    float* out = (float*)d_out;

    const int N = in_sizes[0] / FD;        // 50000
    const int E = in_sizes[1];             // 1600000
    const int NB = (N + RB - 1) / RB;      // 782 (<= NBMAX)
    const int CS = (E + CHUNKS - 1) / CHUNKS;

    char* ws = (char*)d_ws;
    size_t off = 0;
    auto alloc = [&](size_t bytes) -> void* {
        void* p = ws + off;
        off += (bytes + 255) / 256 * 256;
        return p;
    };
    int*   cnt_out = (int*)alloc((size_t)KC * N * 4);
    float* r_out   = (float*)alloc((size_t)N * 4);
    float* r_in    = (float*)alloc((size_t)N * 4);
    int*   hist_g  = (int*)alloc((size_t)CHUNKS * NB * 4);
    int*   cursor  = (int*)alloc((size_t)CHUNKS * NB * 4);
    int*   bstart  = (int*)alloc((size_t)(NB + 1) * 4);
    int*   epack   = (int*)alloc((size_t)E * 4);
    float* z1      = (float*)alloc((size_t)N * FD * 4);
    float* y1      = (float*)alloc((size_t)N * FD * 4);
    float* tbuf    = (float*)alloc((size_t)N * OD * 4);
    float* Wc      = (float*)alloc((size_t)FD * OD * 4);
    float* bc      = (float*)alloc((size_t)OD * 4);
    (void)ws_size; (void)n_in; (void)out_size;

    const int gN = (N + 255) / 256;
    const int gE = (E + 255) / 256;

    // deg_out -> r_out
    zero_kernel<<<(KC * N + 255) / 256, 256, 0, stream>>>(cnt_out, KC * N);
    count_src_kernel<<<gE, 256, 0, stream>>>(src, cnt_out, E, N);
    rout_kernel<<<gN, 256, 0, stream>>>(cnt_out, r_out, N);

    // coarse bucket partition of edges by dst>>6
    bucket_hist_kernel<<<CHUNKS, 256, 0, stream>>>(dst, hist_g, E, NB, CS);
    bucket_scan_kernel<<<1, 1024, 0, stream>>>(hist_g, bstart, NB, E);
    bucket_cursor_kernel<<<(NB + 255) / 256, 256, 0, stream>>>(hist_g, bstart, cursor, NB);
    partition_kernel<<<CHUNKS, 256, 0, stream>>>(src, dst, cursor, epack, E, NB, CS);

    // fold final two linear layers
    fold_kernel<<<(FD * OD + 255) / 256, 256, 0, stream>>>(W2, Wf, b2, bf, Wc, bc);

    // layer 1: z1 = r_in * Agg(r_out * x); y1 = relu(z1@W1 + b1) * r_out
    agg_fused_kernel<FD, true, true, false><<<NB, 512, 0, stream>>>(
        in_feat, r_out, r_in, bstart, epack, (const float*)nullptr, z1, N);
    gemm_kernel<128, 8, 0><<<(N + 127) / 128, 256, 0, stream>>>(z1, W1, b1, r_out, y1, N);

    // layer 2 + final (project to 64 BEFORE aggregating): t = y1@Wc; out = r_in*Agg(t) + bc
    gemm_kernel<64, 4, 2><<<(N + 127) / 128, 256, 0, stream>>>(y1, Wc, bc, (const float*)nullptr, tbuf, N);
    agg_fused_kernel<OD, false, false, true><<<NB, 512, 0, stream>>>(
        tbuf, (const float*)nullptr, r_in, bstart, epack, bc, out, N);
}

// Round 4
// 445.691 us; speedup vs baseline: 5.1166x; 5.1166x over previous
//
#include <hip/hip_runtime.h>

#define FD 128    // hidden feature dim
#define OD 64     // output dim
#define KC 32     // privatized histogram copies for deg_out
#define RB 64     // nodes per bucket (dst >> 6)
#define CHUNKS 256
#define NBMAX 1024

// ---------------- deg_out (privatized histogram) ----------------

__global__ void zero_kernel(int* __restrict__ a, int n) {
    int i = blockIdx.x * 256 + threadIdx.x;
    if (i < n) a[i] = 0;
}

__global__ void count_src_kernel(const int* __restrict__ src, int* __restrict__ cnt,
                                 int E, int N) {
    int e = blockIdx.x * 256 + threadIdx.x;
    int k = blockIdx.x & (KC - 1);
    if (e < E) atomicAdd(&cnt[k * N + src[e]], 1);
}

__global__ void rout_kernel(const int* __restrict__ cnt, float* __restrict__ r_out, int N) {
    int v = blockIdx.x * 256 + threadIdx.x;
    if (v >= N) return;
    int s = 0;
    #pragma unroll
    for (int k = 0; k < KC; k++) s += cnt[k * N + v];
    r_out[v] = rsqrtf((float)max(s, 1));
}

// Xs = r_out (row) * X ; one float4 per thread
__global__ void prescale_kernel(const float* __restrict__ X, const float* __restrict__ r_out,
                                float* __restrict__ Xs, int n4) {
    int i = blockIdx.x * 256 + threadIdx.x;
    if (i >= n4) return;
    int v = i >> 5;                    // 32 float4 per 128-float row
    float r = r_out[v];
    float4 t = ((const float4*)X)[i];
    t.x *= r; t.y *= r; t.z *= r; t.w *= r;
    ((float4*)Xs)[i] = t;
}

// ---------------- coarse bucket partition (counting sort, contention-free) ----------------

__global__ __launch_bounds__(256) void bucket_hist_kernel(const int* __restrict__ dst,
                                                          int* __restrict__ hist_g,
                                                          int E, int NB, int CS) {
    __shared__ int hist[NBMAX];
    int c = blockIdx.x;
    for (int t = threadIdx.x; t < NB; t += 256) hist[t] = 0;
    __syncthreads();
    int e1 = min(c * CS + CS, E);
    for (int e = c * CS + threadIdx.x; e < e1; e += 256)
        atomicAdd(&hist[dst[e] >> 6], 1);
    __syncthreads();
    for (int t = threadIdx.x; t < NB; t += 256) hist_g[c * NB + t] = hist[t];
}

__global__ __launch_bounds__(1024) void bucket_scan_kernel(const int* __restrict__ hist_g,
                                                           int* __restrict__ bstart,
                                                           int NB, int E) {
    __shared__ int wsum[16];
    int tid = threadIdx.x, lane = tid & 63, w = tid >> 6;
    int total = 0;
    if (tid < NB)
        for (int c = 0; c < CHUNKS; c++) total += hist_g[c * NB + tid];
    int x = total;
    #pragma unroll
    for (int d = 1; d < 64; d <<= 1) {
        int t = __shfl_up(x, d, 64);
        if (lane >= d) x += t;
    }
    if (lane == 63) wsum[w] = x;
    __syncthreads();
    if (w == 0) {
        int s = (lane < 16) ? wsum[lane] : 0;
        #pragma unroll
        for (int d = 1; d < 16; d <<= 1) {
            int t = __shfl_up(s, d, 64);
            if (lane >= d) s += t;
        }
        if (lane < 16) wsum[lane] = s;
    }
    __syncthreads();
    int off = (w == 0) ? 0 : wsum[w - 1];
    if (tid < NB) bstart[tid] = x + off - total;
    if (tid == 0) bstart[NB] = E;
}

__global__ void bucket_cursor_kernel(const int* __restrict__ hist_g, const int* __restrict__ bstart,
                                     int* __restrict__ cursor, int NB) {
    int b = blockIdx.x * 256 + threadIdx.x;
    if (b >= NB) return;
    int run = bstart[b];
    for (int c = 0; c < CHUNKS; c++) {
        cursor[c * NB + b] = run;
        run += hist_g[c * NB + b];
    }
}

// scatter packed edges (dl<<17 | src) into bucket runs via LDS cursors
__global__ __launch_bounds__(256) void partition_kernel(const int* __restrict__ src,
                                                        const int* __restrict__ dst,
                                                        const int* __restrict__ cursor,
                                                        int* __restrict__ epack,
                                                        int E, int NB, int CS) {
    __shared__ int cur[NBMAX];
    int c = blockIdx.x;
    for (int t = threadIdx.x; t < NB; t += 256) cur[t] = cursor[c * NB + t];
    __syncthreads();
    int e1 = min(c * CS + CS, E);
    for (int e = c * CS + threadIdx.x; e < e1; e += 256) {
        int d = dst[e];
        int pos = atomicAdd(&cur[d >> 6], 1);
        epack[pos] = ((d & 63) << 17) | src[e];   // src < 2^17
    }
}

// per-bucket LDS counting sort -> exact per-node CSR (csrc) + row_start + r_in
__global__ __launch_bounds__(256) void bucket_sort_kernel(const int* __restrict__ epack,
                                                          const int* __restrict__ bstart,
                                                          int* __restrict__ csrc,
                                                          int* __restrict__ row_start,
                                                          float* __restrict__ r_in,
                                                          int N, int NB, int E) {
    __shared__ int cnt[RB];
    __shared__ int cur[RB];
    int b = blockIdx.x, tid = threadIdx.x;
    int s0 = bstart[b], s1 = bstart[b + 1];
    if (tid < RB) cnt[tid] = 0;
    __syncthreads();
    for (int e = s0 + tid; e < s1; e += 256)
        atomicAdd(&cnt[epack[e] >> 17], 1);
    __syncthreads();
    if (tid < RB) {
        int c = cnt[tid];
        int x = c;
        #pragma unroll
        for (int d = 1; d < 64; d <<= 1) {
            int t = __shfl_up(x, d, 64);
            if (tid >= d) x += t;
        }
        int start = s0 + x - c;            // exclusive
        cur[tid] = start;
        int node = b * RB + tid;
        if (node < N) {
            row_start[node] = start;
            r_in[node] = rsqrtf((float)max(c, 1));
        }
    }
    if (b == NB - 1 && tid == 0) row_start[N] = E;
    __syncthreads();
    for (int e = s0 + tid; e < s1; e += 256) {
        int pk = epack[e];
        int pos = atomicAdd(&cur[pk >> 17], 1);
        csrc[pos] = pk & 0x1FFFF;
    }
}

// ---------------- aggregation: one wave per node, CSR gather ----------------
// Z[v] = r_in[v] * sum_e Xs[csrc[e]]   (Xs pre-scaled by r_out)
__global__ __launch_bounds__(256) void agg128_kernel(const float* __restrict__ Xs,
                                                     const float* __restrict__ r_in,
                                                     const int* __restrict__ rs,
                                                     const int* __restrict__ csrc,
                                                     float* __restrict__ Z, int N) {
    const int lane = threadIdx.x & 63, wv = threadIdx.x >> 6;
    int v = blockIdx.x * 4 + wv;
    if (v >= N) return;
    int s0 = rs[v], s1 = rs[v + 1];
    float ax = 0.f, ay = 0.f;
    int e = s0;
    for (; e + 8 <= s1; e += 8) {
        int idx[8];
        #pragma unroll
        for (int u = 0; u < 8; u++) idx[u] = csrc[e + u];
        float2 t[8];
        #pragma unroll
        for (int u = 0; u < 8; u++)
            t[u] = ((const float2*)(Xs + (size_t)idx[u] * FD))[lane];
        #pragma unroll
        for (int u = 0; u < 8; u++) { ax += t[u].x; ay += t[u].y; }
    }
    for (; e < s1; e++) {
        float2 t = ((const float2*)(Xs + (size_t)csrc[e] * FD))[lane];
        ax += t.x; ay += t.y;
    }
    float ri = r_in[v];
    float2 o; o.x = ax * ri; o.y = ay * ri;
    ((float2*)(Z + (size_t)v * FD))[lane] = o;
}

// out[v] = r_in[v] * sum_e T[csrc[e]] + bc   (64-dim)
__global__ __launch_bounds__(256) void agg64_kernel(const float* __restrict__ T,
                                                    const float* __restrict__ r_in,
                                                    const int* __restrict__ rs,
                                                    const int* __restrict__ csrc,
                                                    const float* __restrict__ bc,
                                                    float* __restrict__ out, int N) {
    const int lane = threadIdx.x & 63, wv = threadIdx.x >> 6;
    int v = blockIdx.x * 4 + wv;
    if (v >= N) return;
    int s0 = rs[v], s1 = rs[v + 1];
    float a = 0.f;
    int e = s0;
    for (; e + 8 <= s1; e += 8) {
        int idx[8];
        #pragma unroll
        for (int u = 0; u < 8; u++) idx[u] = csrc[e + u];
        float t[8];
        #pragma unroll
        for (int u = 0; u < 8; u++) t[u] = T[(size_t)idx[u] * OD + lane];
        #pragma unroll
        for (int u = 0; u < 8; u++) a += t[u];
    }
    for (; e < s1; e++) a += T[(size_t)csrc[e] * OD + lane];
    out[(size_t)v * OD + lane] = a * r_in[v] + bc[lane];
}

// ---------------- GEMM: C(MxBN) = A(Mx128) * B(128xBN) + epilogue ----------------
// EPI 0: C = relu(acc + bias[col]) * rowscale[row] ;  EPI 2: C = acc
template <int BN, int TN, int EPI>
__global__ __launch_bounds__(256) void gemm_kernel(const float* __restrict__ A,
                                                   const float* __restrict__ B,
                                                   const float* __restrict__ bias,
                                                   const float* __restrict__ rowscale,
                                                   float* __restrict__ C, int M) {
    __shared__ float As[8][128];
    __shared__ float Bs[8][BN];
    const int tid = threadIdx.x;
    const int blk0 = blockIdx.x * 128;
    const int tr = tid >> 4;
    const int tc = tid & 15;

    float acc[8][TN];
    #pragma unroll
    for (int i = 0; i < 8; i++)
        #pragma unroll
        for (int j = 0; j < TN; j++) acc[i][j] = 0.f;

    const int lm = tid >> 1;
    const int lka = (tid & 1) * 4;
    const int arow = blk0 + lm;
    constexpr int bthr = (8 * BN) / 256;
    const int lkb = tid / (BN / bthr);
    const int lnb = (tid % (BN / bthr)) * bthr;

    for (int k0 = 0; k0 < 128; k0 += 8) {
        float4 av = make_float4(0.f, 0.f, 0.f, 0.f);
        if (arow < M) av = *(const float4*)(A + (size_t)arow * 128 + k0 + lka);
        float bv[bthr];
        #pragma unroll
        for (int j = 0; j < bthr; j++) bv[j] = B[(k0 + lkb) * BN + lnb + j];
        __syncthreads();
        As[lka + 0][lm] = av.x;
        As[lka + 1][lm] = av.y;
        As[lka + 2][lm] = av.z;
        As[lka + 3][lm] = av.w;
        #pragma unroll
        for (int j = 0; j < bthr; j++) Bs[lkb][lnb + j] = bv[j];
        __syncthreads();
        #pragma unroll
        for (int kk = 0; kk < 8; kk++) {
            float a[8], bb[TN];
            #pragma unroll
            for (int i = 0; i < 8; i++) a[i] = As[kk][tr * 8 + i];
            #pragma unroll
            for (int j = 0; j < TN; j++) bb[j] = Bs[kk][tc * TN + j];
            #pragma unroll
            for (int i = 0; i < 8; i++)
                #pragma unroll
                for (int j = 0; j < TN; j++) acc[i][j] += a[i] * bb[j];
        }
    }

    #pragma unroll
    for (int i = 0; i < 8; i++) {
        int row = blk0 + tr * 8 + i;
        if (row < M) {
            float rsc = (EPI == 0) ? rowscale[row] : 1.f;
            #pragma unroll
            for (int j = 0; j < TN; j++) {
                float vv = acc[i][j];
                if (EPI == 0) vv = fmaxf(vv + bias[tc * TN + j], 0.f) * rsc;
                C[(size_t)row * BN + tc * TN + j] = vv;
            }
        }
    }
}

// ---------------- fold W2@Wf, b2@Wf+bf ----------------
__global__ void fold_kernel(const float* __restrict__ W2, const float* __restrict__ Wf,
                            const float* __restrict__ b2, const float* __restrict__ bf,
                            float* __restrict__ Wc, float* __restrict__ bc) {
    int idx = blockIdx.x * 256 + threadIdx.x;
    if (idx < FD * OD) {
        int i = idx / OD, j = idx % OD;
        float s = 0.f;
        for (int k = 0; k < FD; k++) s += W2[i * FD + k] * Wf[k * OD + j];
        Wc[idx] = s;
    }
    if (idx < OD) {
        float s = bf[idx];
        for (int k = 0; k < FD; k++) s += b2[k] * Wf[k * OD + idx];
        bc[idx] = s;
    }
}

// ---------------- launch ----------------
extern "C" void kernel_launch(void* const* d_in, const int* in_sizes, int n_in,
                              void* d_out, int out_size, void* d_ws, size_t ws_size,
                              hipStream_t stream) {
    const float* in_feat = (const float*)d_in[0];
    const int*   src     = (const int*)d_in[1];
    const int*   dst     = (const int*)d_in[2];
    const float* W1      = (const float*)d_in[3];
    const float* b1      = (const float*)d_in[4];
    const float* W2      = (const float*)d_in[5];
    const float* b2      = (const float*)d_in[6];
    const float* Wf      = (const float*)d_in[7];
    const float* bf      = (const float*)d_in[8];
    float* out = (float*)d_out;

    const int N = in_sizes[0] / FD;        // 50000
    const int E = in_sizes[1];             // 1600000
    const int NB = (N + RB - 1) / RB;      // 782 (<= NBMAX)
    const int CS = (E + CHUNKS - 1) / CHUNKS;

    char* ws = (char*)d_ws;
    size_t off = 0;
    auto alloc = [&](size_t bytes) -> void* {
        void* p = ws + off;
        off += (bytes + 255) / 256 * 256;
        return p;
    };
    // cnt_out and epack are adjacent and both dead by the time gemm2 runs;
    // tbuf (N*OD*4 = 12.8 MB) aliases their combined 12.8 MB.
    int*   cnt_out = (int*)alloc((size_t)KC * N * 4);   // 6.4 MB, dead after rout
    int*   epack   = (int*)alloc((size_t)E * 4);        // 6.4 MB, dead after bucket_sort
    float* tbuf    = (float*)cnt_out;
    float* r_out   = (float*)alloc((size_t)N * 4);
    float* r_in    = (float*)alloc((size_t)N * 4);
    int*   hist_g  = (int*)alloc((size_t)CHUNKS * NB * 4);
    int*   cursor  = (int*)alloc((size_t)CHUNKS * NB * 4);
    int*   bstart  = (int*)alloc((size_t)(NB + 1) * 4);
    int*   csrc    = (int*)alloc((size_t)E * 4);
    int*   row_start = (int*)alloc((size_t)(N + 1) * 4);
    float* z1      = (float*)alloc((size_t)N * FD * 4);
    float* y1      = (float*)alloc((size_t)N * FD * 4); // doubles as Xs before gemm1
    float* Wc      = (float*)alloc((size_t)FD * OD * 4);
    float* bc      = (float*)alloc((size_t)OD * 4);
    float* Xs      = y1;
    (void)ws_size; (void)n_in; (void)out_size;

    const int gN = (N + 255) / 256;
    const int gE = (E + 255) / 256;

    // deg_out -> r_out
    zero_kernel<<<(KC * N + 255) / 256, 256, 0, stream>>>(cnt_out, KC * N);
    count_src_kernel<<<gE, 256, 0, stream>>>(src, cnt_out, E, N);
    rout_kernel<<<gN, 256, 0, stream>>>(cnt_out, r_out, N);

    // exact dst-sort: coarse bucket partition + per-bucket LDS counting sort
    bucket_hist_kernel<<<CHUNKS, 256, 0, stream>>>(dst, hist_g, E, NB, CS);
    bucket_scan_kernel<<<1, 1024, 0, stream>>>(hist_g, bstart, NB, E);
    bucket_cursor_kernel<<<(NB + 255) / 256, 256, 0, stream>>>(hist_g, bstart, cursor, NB);
    partition_kernel<<<CHUNKS, 256, 0, stream>>>(src, dst, cursor, epack, E, NB, CS);
    bucket_sort_kernel<<<NB, 256, 0, stream>>>(epack, bstart, csrc, row_start, r_in, N, NB, E);

    // fold final two linear layers
    fold_kernel<<<(FD * OD + 255) / 256, 256, 0, stream>>>(W2, Wf, b2, bf, Wc, bc);

    // layer 1: Xs = r_out*x ; z1 = r_in*Agg(Xs) ; y1 = relu(z1@W1+b1)*r_out
    prescale_kernel<<<(N * 32 + 255) / 256, 256, 0, stream>>>(in_feat, r_out, Xs, N * 32);
    agg128_kernel<<<(N + 3) / 4, 256, 0, stream>>>(Xs, r_in, row_start, csrc, z1, N);
    gemm_kernel<128, 8, 0><<<(N + 127) / 128, 256, 0, stream>>>(z1, W1, b1, r_out, y1, N);

    // layer 2 + final (project to 64 BEFORE aggregating): t = y1@Wc ; out = r_in*Agg(t)+bc
    gemm_kernel<64, 4, 2><<<(N + 127) / 128, 256, 0, stream>>>(y1, Wc, bc, (const float*)nullptr, tbuf, N);
    agg64_kernel<<<(N + 3) / 4, 256, 0, stream>>>(tbuf, r_in, row_start, csrc, bc, out, N);
}

// Round 5
// 371.635 us; speedup vs baseline: 6.1362x; 1.1993x over previous
//
#include <hip/hip_runtime.h>
#include <hip/hip_fp16.h>

#define FD 128    // hidden feature dim
#define OD 64     // output dim
#define KC 32     // privatized histogram copies for deg_out
#define RB 64     // nodes per bucket (dst >> 6)
#define CHUNKS 256
#define NBMAX 1024

// ---------------- misc ----------------

__global__ void zero_kernel(int* __restrict__ a, int n) {
    int i = blockIdx.x * 256 + threadIdx.x;
    if (i < n) a[i] = 0;
}

__global__ void rout_kernel(const int* __restrict__ cnt, float* __restrict__ r_out, int N) {
    int v = blockIdx.x * 256 + threadIdx.x;
    if (v >= N) return;
    int s = 0;
    #pragma unroll
    for (int k = 0; k < KC; k++) s += cnt[k * N + v];
    r_out[v] = rsqrtf((float)max(s, 1));
}

// Xs(half) = r_out (row) * X ; one float4 -> 4 halves per thread
__global__ void prescale_kernel(const float* __restrict__ X, const float* __restrict__ r_out,
                                __half* __restrict__ Xs, int n4) {
    int i = blockIdx.x * 256 + threadIdx.x;
    if (i >= n4) return;
    int v = i >> 5;                    // 32 float4 per 128-float row
    float r = r_out[v];
    float4 t = ((const float4*)X)[i];
    __half2 h0 = __floats2half2_rn(t.x * r, t.y * r);
    __half2 h1 = __floats2half2_rn(t.z * r, t.w * r);
    ((__half2*)Xs)[2 * i]     = h0;
    ((__half2*)Xs)[2 * i + 1] = h1;
}

// ---------------- coarse bucket partition (counting sort, contention-free) ----------------

__global__ __launch_bounds__(256) void bucket_hist_kernel(const int* __restrict__ dst,
                                                          int* __restrict__ hist_g,
                                                          int E, int NB, int CS) {
    __shared__ int hist[NBMAX];
    int c = blockIdx.x;
    for (int t = threadIdx.x; t < NB; t += 256) hist[t] = 0;
    __syncthreads();
    int e1 = min(c * CS + CS, E);
    for (int e = c * CS + threadIdx.x; e < e1; e += 256)
        atomicAdd(&hist[dst[e] >> 6], 1);
    __syncthreads();
    for (int t = threadIdx.x; t < NB; t += 256) hist_g[c * NB + t] = hist[t];
}

__global__ __launch_bounds__(1024) void bucket_scan_kernel(const int* __restrict__ hist_g,
                                                           int* __restrict__ bstart,
                                                           int NB, int E) {
    __shared__ int wsum[16];
    int tid = threadIdx.x, lane = tid & 63, w = tid >> 6;
    int total = 0;
    if (tid < NB)
        for (int c = 0; c < CHUNKS; c++) total += hist_g[c * NB + tid];
    int x = total;
    #pragma unroll
    for (int d = 1; d < 64; d <<= 1) {
        int t = __shfl_up(x, d, 64);
        if (lane >= d) x += t;
    }
    if (lane == 63) wsum[w] = x;
    __syncthreads();
    if (w == 0) {
        int s = (lane < 16) ? wsum[lane] : 0;
        #pragma unroll
        for (int d = 1; d < 16; d <<= 1) {
            int t = __shfl_up(s, d, 64);
            if (lane >= d) s += t;
        }
        if (lane < 16) wsum[lane] = s;
    }
    __syncthreads();
    int off = (w == 0) ? 0 : wsum[w - 1];
    if (tid < NB) bstart[tid] = x + off - total;
    if (tid == 0) bstart[NB] = E;
}

__global__ void bucket_cursor_kernel(const int* __restrict__ hist_g, const int* __restrict__ bstart,
                                     int* __restrict__ cursor, int NB) {
    int b = blockIdx.x * 256 + threadIdx.x;
    if (b >= NB) return;
    int run = bstart[b];
    for (int c = 0; c < CHUNKS; c++) {
        cursor[c * NB + b] = run;
        run += hist_g[c * NB + b];
    }
}

// scatter packed edges (dl<<17 | src) into bucket runs via LDS cursors;
// fused: also builds the KC-privatized src histogram (deg_out) since src[e]
// is already in hand (k = blockIdx % KC keeps blockIdx%8 XCD alignment).
__global__ __launch_bounds__(256) void partition_kernel(const int* __restrict__ src,
                                                        const int* __restrict__ dst,
                                                        const int* __restrict__ cursor,
                                                        int* __restrict__ epack,
                                                        int* __restrict__ cnt_src,
                                                        int E, int NB, int CS, int N) {
    __shared__ int cur[NBMAX];
    int c = blockIdx.x;
    int k = blockIdx.x & (KC - 1);
    for (int t = threadIdx.x; t < NB; t += 256) cur[t] = cursor[c * NB + t];
    __syncthreads();
    int e1 = min(c * CS + CS, E);
    for (int e = c * CS + threadIdx.x; e < e1; e += 256) {
        int d = dst[e];
        int s = src[e];
        int pos = atomicAdd(&cur[d >> 6], 1);
        epack[pos] = ((d & 63) << 17) | s;   // src < 2^17
        atomicAdd(&cnt_src[k * N + s], 1);
    }
}

// per-bucket LDS counting sort -> exact per-node CSR (csrc) + row_start + r_in
__global__ __launch_bounds__(256) void bucket_sort_kernel(const int* __restrict__ epack,
                                                          const int* __restrict__ bstart,
                                                          int* __restrict__ csrc,
                                                          int* __restrict__ row_start,
                                                          float* __restrict__ r_in,
                                                          int N, int NB, int E) {
    __shared__ int cnt[RB];
    __shared__ int cur[RB];
    int b = blockIdx.x, tid = threadIdx.x;
    int s0 = bstart[b], s1 = bstart[b + 1];
    if (tid < RB) cnt[tid] = 0;
    __syncthreads();
    for (int e = s0 + tid; e < s1; e += 256)
        atomicAdd(&cnt[epack[e] >> 17], 1);
    __syncthreads();
    if (tid < RB) {
        int c = cnt[tid];
        int x = c;
        #pragma unroll
        for (int d = 1; d < 64; d <<= 1) {
            int t = __shfl_up(x, d, 64);
            if (tid >= d) x += t;
        }
        int start = s0 + x - c;            // exclusive
        cur[tid] = start;
        int node = b * RB + tid;
        if (node < N) {
            row_start[node] = start;
            r_in[node] = rsqrtf((float)max(c, 1));
        }
    }
    if (b == NB - 1 && tid == 0) row_start[N] = E;
    __syncthreads();
    for (int e = s0 + tid; e < s1; e += 256) {
        int pk = epack[e];
        int pos = atomicAdd(&cur[pk >> 17], 1);
        csrc[pos] = pk & 0x1FFFF;
    }
}

// ---------------- aggregation: one wave per node, CSR gather (fp16 rows) ----------------
// Z[v] = r_in[v] * sum_e Xs[csrc[e]]   (Xs pre-scaled by r_out, fp16)
__global__ __launch_bounds__(256) void agg128_kernel(const __half* __restrict__ Xs,
                                                     const float* __restrict__ r_in,
                                                     const int* __restrict__ rs,
                                                     const int* __restrict__ csrc,
                                                     float* __restrict__ Z, int N) {
    const int lane = threadIdx.x & 63, wv = threadIdx.x >> 6;
    int v = blockIdx.x * 4 + wv;
    if (v >= N) return;
    int s0 = rs[v], s1 = rs[v + 1];
    float ax = 0.f, ay = 0.f;
    int e = s0;
    for (; e + 8 <= s1; e += 8) {
        int idx[8];
        #pragma unroll
        for (int u = 0; u < 8; u++) idx[u] = csrc[e + u];
        __half2 t[8];
        #pragma unroll
        for (int u = 0; u < 8; u++)
            t[u] = ((const __half2*)(Xs + (size_t)idx[u] * FD))[lane];
        #pragma unroll
        for (int u = 0; u < 8; u++) {
            float2 f = __half22float2(t[u]);
            ax += f.x; ay += f.y;
        }
    }
    for (; e < s1; e++) {
        float2 f = __half22float2(((const __half2*)(Xs + (size_t)csrc[e] * FD))[lane]);
        ax += f.x; ay += f.y;
    }
    float ri = r_in[v];
    float2 o; o.x = ax * ri; o.y = ay * ri;
    ((float2*)(Z + (size_t)v * FD))[lane] = o;
}

// out[v] = r_in[v] * sum_e T[csrc[e]] + bc   (64-dim, fp16 rows)
__global__ __launch_bounds__(256) void agg64_kernel(const __half* __restrict__ T,
                                                    const float* __restrict__ r_in,
                                                    const int* __restrict__ rs,
                                                    const int* __restrict__ csrc,
                                                    const float* __restrict__ bc,
                                                    float* __restrict__ out, int N) {
    const int lane = threadIdx.x & 63, wv = threadIdx.x >> 6;
    int v = blockIdx.x * 4 + wv;
    if (v >= N) return;
    int s0 = rs[v], s1 = rs[v + 1];
    float a = 0.f;
    int e = s0;
    for (; e + 8 <= s1; e += 8) {
        int idx[8];
        #pragma unroll
        for (int u = 0; u < 8; u++) idx[u] = csrc[e + u];
        __half t[8];
        #pragma unroll
        for (int u = 0; u < 8; u++) t[u] = T[(size_t)idx[u] * OD + lane];
        #pragma unroll
        for (int u = 0; u < 8; u++) a += __half2float(t[u]);
    }
    for (; e < s1; e++) a += __half2float(T[(size_t)csrc[e] * OD + lane]);
    out[(size_t)v * OD + lane] = a * r_in[v] + bc[lane];
}

// ---------------- GEMM: C(MxBN) = A(Mx128) * B(128xBN) + epilogue ----------------
// EPI 0: C = relu(acc + bias[col]) * rowscale[row] (CT=float)
// EPI 2: C = acc (CT may be __half)
template <int BN, int TN, int EPI, typename CT>
__global__ __launch_bounds__(256) void gemm_kernel(const float* __restrict__ A,
                                                   const float* __restrict__ B,
                                                   const float* __restrict__ bias,
                                                   const float* __restrict__ rowscale,
                                                   CT* __restrict__ C, int M) {
    __shared__ float As[8][128];
    __shared__ float Bs[8][BN];
    const int tid = threadIdx.x;
    const int blk0 = blockIdx.x * 128;
    const int tr = tid >> 4;
    const int tc = tid & 15;

    float acc[8][TN];
    #pragma unroll
    for (int i = 0; i < 8; i++)
        #pragma unroll
        for (int j = 0; j < TN; j++) acc[i][j] = 0.f;

    const int lm = tid >> 1;
    const int lka = (tid & 1) * 4;
    const int arow = blk0 + lm;
    constexpr int bthr = (8 * BN) / 256;
    const int lkb = tid / (BN / bthr);
    const int lnb = (tid % (BN / bthr)) * bthr;

    for (int k0 = 0; k0 < 128; k0 += 8) {
        float4 av = make_float4(0.f, 0.f, 0.f, 0.f);
        if (arow < M) av = *(const float4*)(A + (size_t)arow * 128 + k0 + lka);
        float bv[bthr];
        #pragma unroll
        for (int j = 0; j < bthr; j++) bv[j] = B[(k0 + lkb) * BN + lnb + j];
        __syncthreads();
        As[lka + 0][lm] = av.x;
        As[lka + 1][lm] = av.y;
        As[lka + 2][lm] = av.z;
        As[lka + 3][lm] = av.w;
        #pragma unroll
        for (int j = 0; j < bthr; j++) Bs[lkb][lnb + j] = bv[j];
        __syncthreads();
        #pragma unroll
        for (int kk = 0; kk < 8; kk++) {
            float a[8], bb[TN];
            #pragma unroll
            for (int i = 0; i < 8; i++) a[i] = As[kk][tr * 8 + i];
            #pragma unroll
            for (int j = 0; j < TN; j++) bb[j] = Bs[kk][tc * TN + j];
            #pragma unroll
            for (int i = 0; i < 8; i++)
                #pragma unroll
                for (int j = 0; j < TN; j++) acc[i][j] += a[i] * bb[j];
        }
    }

    #pragma unroll
    for (int i = 0; i < 8; i++) {
        int row = blk0 + tr * 8 + i;
        if (row < M) {
            float rsc = (EPI == 0) ? rowscale[row] : 1.f;
            #pragma unroll
            for (int j = 0; j < TN; j++) {
                float vv = acc[i][j];
                if (EPI == 0) vv = fmaxf(vv + bias[tc * TN + j], 0.f) * rsc;
                C[(size_t)row * BN + tc * TN + j] = (CT)vv;
            }
        }
    }
}

// ---------------- fold W2@Wf, b2@Wf+bf ----------------
__global__ void fold_kernel(const float* __restrict__ W2, const float* __restrict__ Wf,
                            const float* __restrict__ b2, const float* __restrict__ bf,
                            float* __restrict__ Wc, float* __restrict__ bc) {
    int idx = blockIdx.x * 256 + threadIdx.x;
    if (idx < FD * OD) {
        int i = idx / OD, j = idx % OD;
        float s = 0.f;
        for (int k = 0; k < FD; k++) s += W2[i * FD + k] * Wf[k * OD + j];
        Wc[idx] = s;
    }
    if (idx < OD) {
        float s = bf[idx];
        for (int k = 0; k < FD; k++) s += b2[k] * Wf[k * OD + idx];
        bc[idx] = s;
    }
}

// ---------------- launch ----------------
extern "C" void kernel_launch(void* const* d_in, const int* in_sizes, int n_in,
                              void* d_out, int out_size, void* d_ws, size_t ws_size,
                              hipStream_t stream) {
    const float* in_feat = (const float*)d_in[0];
    const int*   src     = (const int*)d_in[1];
    const int*   dst     = (const int*)d_in[2];
    const float* W1      = (const float*)d_in[3];
    const float* b1      = (const float*)d_in[4];
    const float* W2      = (const float*)d_in[5];
    const float* b2      = (const float*)d_in[6];
    const float* Wf      = (const float*)d_in[7];
    const float* bf      = (const float*)d_in[8];
    float* out = (float*)d_out;

    const int N = in_sizes[0] / FD;        // 50000
    const int E = in_sizes[1];             // 1600000
    const int NB = (N + RB - 1) / RB;      // 782 (<= NBMAX)
    const int CS = (E + CHUNKS - 1) / CHUNKS;

    char* ws = (char*)d_ws;
    size_t off = 0;
    auto alloc = [&](size_t bytes) -> void* {
        void* p = ws + off;
        off += (bytes + 255) / 256 * 256;
        return p;
    };
    // cnt_out (6.4 MB) dead after rout; tbuf (N*OD*2 = 6.4 MB half) aliases it.
    int*    cnt_out = (int*)alloc((size_t)KC * N * 4);
    __half* tbuf    = (__half*)cnt_out;
    int*    epack   = (int*)alloc((size_t)E * 4);        // dead after bucket_sort
    float*  r_out   = (float*)alloc((size_t)N * 4);
    float*  r_in    = (float*)alloc((size_t)N * 4);
    int*    hist_g  = (int*)alloc((size_t)CHUNKS * NB * 4);
    int*    cursor  = (int*)alloc((size_t)CHUNKS * NB * 4);
    int*    bstart  = (int*)alloc((size_t)(NB + 1) * 4);
    int*    csrc    = (int*)alloc((size_t)E * 4);
    int*    row_start = (int*)alloc((size_t)(N + 1) * 4);
    float*  z1      = (float*)alloc((size_t)N * FD * 4);
    float*  y1      = (float*)alloc((size_t)N * FD * 4); // fp32; Xs(half) aliases it
    float*  Wc      = (float*)alloc((size_t)FD * OD * 4);
    float*  bc      = (float*)alloc((size_t)OD * 4);
    __half* Xs      = (__half*)y1;                       // dead before gemm1 writes y1
    (void)ws_size; (void)n_in; (void)out_size;

    const int gN = (N + 255) / 256;

    // exact dst-sort: coarse bucket partition + per-bucket LDS counting sort.
    // partition also builds the privatized src histogram (deg_out).
    zero_kernel<<<(KC * N + 255) / 256, 256, 0, stream>>>(cnt_out, KC * N);
    bucket_hist_kernel<<<CHUNKS, 256, 0, stream>>>(dst, hist_g, E, NB, CS);
    bucket_scan_kernel<<<1, 1024, 0, stream>>>(hist_g, bstart, NB, E);
    bucket_cursor_kernel<<<(NB + 255) / 256, 256, 0, stream>>>(hist_g, bstart, cursor, NB);
    partition_kernel<<<CHUNKS, 256, 0, stream>>>(src, dst, cursor, epack, cnt_out, E, NB, CS, N);
    bucket_sort_kernel<<<NB, 256, 0, stream>>>(epack, bstart, csrc, row_start, r_in, N, NB, E);
    rout_kernel<<<gN, 256, 0, stream>>>(cnt_out, r_out, N);

    // fold final two linear layers
    fold_kernel<<<(FD * OD + 255) / 256, 256, 0, stream>>>(W2, Wf, b2, bf, Wc, bc);

    // layer 1: Xs = half(r_out*x) ; z1 = r_in*Agg(Xs) ; y1 = relu(z1@W1+b1)*r_out
    prescale_kernel<<<(N * 32 + 255) / 256, 256, 0, stream>>>(in_feat, r_out, Xs, N * 32);
    agg128_kernel<<<(N + 3) / 4, 256, 0, stream>>>(Xs, r_in, row_start, csrc, z1, N);
    gemm_kernel<128, 8, 0, float><<<(N + 127) / 128, 256, 0, stream>>>(z1, W1, b1, r_out, y1, N);

    // layer 2 + final (project to 64 BEFORE aggregating): t = half(y1@Wc) ; out = r_in*Agg(t)+bc
    gemm_kernel<64, 4, 2, __half><<<(N + 127) / 128, 256, 0, stream>>>(y1, Wc, bc, (const float*)nullptr, tbuf, N);
    agg64_kernel<<<(N + 3) / 4, 256, 0, stream>>>(tbuf, r_in, row_start, csrc, bc, out, N);
}